// Round 6
// baseline (533.802 us; speedup 1.0000x reference)
//
#include <hip/hip_runtime.h>

// out[c,i,j] = one_hot[i,c]   (c<4)   — row broadcast
// out[c,i,j] = one_hot[j,c-4] (c>=4)  — column broadcast
// L=4096, one_hot [L,4] f32, out [8,L,L] f32 (512 MiB, pure write-BW bound).
//
// R3: long-lived blocks, 64 f32x4 stores/thread: 630->518 us.
// R5: nontemporal stores: neutral (514) -> L2 churn not the limiter.
// R6: clone rocclr fillBuffer's access pattern exactly: flat GRID-STRIDE sweep
//     so all waves write inside one moving ~8 MiB window (DRAM row-buffer
//     locality) instead of 2048 scattered 256 KiB streams. Bottom-channel
//     values come from a 16 KiB LDS byte map (one_hot is exactly 0/1),
//     one dword read + cvt_f32_ubyte per f32x4 store.

typedef float f32x4 __attribute__((ext_vector_type(4)));

constexpr int L     = 4096;
constexpr int NB    = 4;
constexpr int NBLK  = 2048;
constexpr int NTHR  = 256;
constexpr int TOT4  = 8 * L * (L / 4);          // 2^25 f32x4 elements
constexpr int STRIDE = NBLK * NTHR;             // 2^19
constexpr int ITERS  = TOT4 / STRIDE;           // 64

__global__ __launch_bounds__(256) void seq_embed(const f32x4* __restrict__ oh4,
                                                 float* __restrict__ out) {
    __shared__ unsigned char ohT[NB][L];        // 16 KiB: ohT[c][j] = (one_hot[j][c] != 0)
    const int t = threadIdx.x;

    // stage transposed byte map (coalesced f32x4 loads, once per block)
#pragma unroll
    for (int k = 0; k < L / NTHR; ++k) {        // 16
        const int p = t + NTHR * k;
        const f32x4 w = oh4[p];                 // one_hot row p (16 B, lane-consec)
        ohT[0][p] = (unsigned char)(w.x != 0.0f);
        ohT[1][p] = (unsigned char)(w.y != 0.0f);
        ohT[2][p] = (unsigned char)(w.z != 0.0f);
        ohT[3][p] = (unsigned char)(w.w != 0.0f);
    }
    __syncthreads();

    const float* oh = reinterpret_cast<const float*>(oh4);
    f32x4* __restrict__ out4 = reinterpret_cast<f32x4*>(out);
    const int base = blockIdx.x * NTHR + t;     // < 2^19

#pragma unroll 8
    for (int it = 0; it < ITERS; ++it) {
        const int idx = base + it * STRIDE;     // f32x4 index, < 2^25
        const int row = idx >> 10;              // 1024 f32x4 per row
        const int c   = row >> 12;              // channel (wave-uniform)
        const int i   = row & (L - 1);
        const int j4  = idx & 1023;
        f32x4 v;
        if (c < NB) {
            const float s = oh[i * NB + c];     // same addr across wave: broadcast
            v = (f32x4){s, s, s, s};
        } else {
            const unsigned u =
                *reinterpret_cast<const unsigned*>(&ohT[c - NB][4 * j4]);
            v.x = (float)((u)       & 0xff);    // v_cvt_f32_ubyte0..3
            v.y = (float)((u >> 8)  & 0xff);
            v.z = (float)((u >> 16) & 0xff);
            v.w = (float)((u >> 24) & 0xff);
        }
        __builtin_nontemporal_store(v, &out4[idx]);
    }
}

extern "C" void kernel_launch(void* const* d_in, const int* in_sizes, int n_in,
                              void* d_out, int out_size, void* d_ws, size_t ws_size,
                              hipStream_t stream) {
    const f32x4* oh4 = (const f32x4*)d_in[0];
    float* out = (float*)d_out;
    seq_embed<<<NBLK, NTHR, 0, stream>>>(oh4, out);
}